// Round 1
// 299.528 us; speedup vs baseline: 1.0533x; 1.0533x over previous
//
#include <hip/hip_runtime.h>
#include <hip/hip_bf16.h>
#include <stdint.h>

typedef short bf16x8 __attribute__((ext_vector_type(8)));
typedef float f32x4 __attribute__((ext_vector_type(4)));
typedef unsigned short ushort_t;
typedef unsigned int uint_t;

#define CIN   256
#define COUT  256
#define HWDIM 56
#define IMG   (HWDIM * HWDIM)   // 3136
#define K_TOT (CIN * 9)         // 2304
#define NIMG  32
#define NPIX  (NIMG * IMG)      // 100352
#define BM    128
#define BN    128
#define NSTEP 18                 // 2 c-halves x 9 kpos, BK=128 per step

#define AS1CAST(p) ((const __attribute__((address_space(1))) unsigned int*)(uintptr_t)(p))
#define AS3CAST(p) ((__attribute__((address_space(3))) unsigned int*)(uintptr_t)(p))

__device__ __forceinline__ ushort_t f2bf(float f) {
    union { float f; uint_t u; } v; v.f = f;
    uint_t u = v.u;
    uint_t r = u + 0x7FFFu + ((u >> 16) & 1u);   // RNE
    return (ushort_t)(r >> 16);
}

// ---------------------------------------------------------------------------
// Ternarize: per-filter delta/alpha; signs as exact bf16 into wt2[o][kpos][c].
// Block 0 also zeroes the xt halo pad row (row NPIX).
// ---------------------------------------------------------------------------
__global__ __launch_bounds__(256) void ternarize_kernel(
        const float* __restrict__ w,
        ushort_t* __restrict__ wt2,
        float* __restrict__ alpha_out,
        ushort_t* __restrict__ xt_pad_row) {
    const int o = blockIdx.x;
    const int t = threadIdx.x;
    const int lane = t & 63;
    const int wv = t >> 6;
    const float* base = w + (size_t)o * K_TOT;

    if (o == 0 && t < 32) ((uint4*)xt_pad_row)[t] = (uint4){0u, 0u, 0u, 0u};

    float v[9];
#pragma unroll
    for (int i = 0; i < 9; ++i) v[i] = base[t + 256 * i];

    __shared__ float sred[8];

    float s = 0.f;
#pragma unroll
    for (int i = 0; i < 9; ++i) s += fabsf(v[i]);
#pragma unroll
    for (int off = 32; off > 0; off >>= 1) s += __shfl_down(s, off);
    if (lane == 0) sred[wv] = s;
    __syncthreads();
    if (t == 0) sred[0] = sred[0] + sred[1] + sred[2] + sred[3];
    __syncthreads();
    const float delta = (0.7f / (float)K_TOT) * sred[0];
    __syncthreads();

    float asum = 0.f, cnt = 0.f;
#pragma unroll
    for (int i = 0; i < 9; ++i) {
        float a = fabsf(v[i]);
        if (a > delta) { asum += a; cnt += 1.f; }
    }
#pragma unroll
    for (int off = 32; off > 0; off >>= 1) {
        asum += __shfl_down(asum, off);
        cnt  += __shfl_down(cnt, off);
    }
    if (lane == 0) { sred[wv] = asum; sred[4 + wv] = cnt; }
    __syncthreads();
    if (t == 0) {
        float at = sred[0] + sred[1] + sred[2] + sred[3];
        float ct = sred[4] + sred[5] + sred[6] + sred[7];
        alpha_out[o] = at / ct;
    }

#pragma unroll
    for (int i = 0; i < 9; ++i) {
        int idx = t + 256 * i;           // flat k = c*9 + r
        int c = idx / 9;
        int r = idx - c * 9;
        float x = v[i];
        ushort_t bits = 0;
        if (x > delta)       bits = 0x3F80u;
        else if (x < -delta) bits = 0xBF80u;
        wt2[(size_t)o * K_TOT + r * 256 + c] = bits;
    }
}

// ---------------------------------------------------------------------------
// Transpose + convert: x NCHW fp32 -> xt [pixel][channel] bf16.
// ---------------------------------------------------------------------------
__global__ __launch_bounds__(256) void transpose_kernel(
        const float* __restrict__ x, ushort_t* __restrict__ xt) {
    __shared__ float L[32][132];
    const int hw0 = blockIdx.x * 32;
    const int c0  = blockIdx.y * 128;
    const int n   = blockIdx.z;
    const int t = threadIdx.x;
    const int c_ = t >> 1;        // 0..127
    const int half = t & 1;

    const float* src = x + (size_t)(n * CIN + c0 + c_) * IMG + hw0 + half * 16;
    float4 v[4];
#pragma unroll
    for (int k = 0; k < 4; ++k) v[k] = *(const float4*)(src + k * 4);
#pragma unroll
    for (int k = 0; k < 4; ++k) {
        L[half * 16 + k * 4 + 0][c_] = v[k].x;
        L[half * 16 + k * 4 + 1][c_] = v[k].y;
        L[half * 16 + k * 4 + 2][c_] = v[k].z;
        L[half * 16 + k * 4 + 3][c_] = v[k].w;
    }
    __syncthreads();

    const int seg = t & 15;       // 8-channel segment
    const int hwb = t >> 4;       // 0..15
#pragma unroll
    for (int j = 0; j < 2; ++j) {
        const int hwl = hwb + j * 16;
        const float* row = &L[hwl][seg * 8];
        uint_t pk[4];
#pragma unroll
        for (int q = 0; q < 4; ++q)
            pk[q] = (uint_t)f2bf(row[2 * q]) | ((uint_t)f2bf(row[2 * q + 1]) << 16);
        *(uint4*)&xt[(size_t)(n * IMG + hw0 + hwl) * CIN + c0 + seg * 8] =
            (uint4){pk[0], pk[1], pk[2], pk[3]};
    }
}

// ---------------------------------------------------------------------------
// Implicit-GEMM conv, 4-phase counted-vmcnt ring (T3+T4+T5).
// 128x128 tile, BK=128 per step (one kpos x 64-ch half-slots), 18 K-steps.
// LDS: As/Xs[2 half-slots][128 rows][64 ch] = 64 KB -> 2 blocks/CU.
// Per step, phases:
//   P0: ds_read all kh0 frags (both 32-ch chunks)   | barrier | 16 MFMA (kk0)
//   P1: stage KH0(s+1) 8 loads; s_waitcnt vmcnt(8)  | barrier | 16 MFMA (kk1)
//   P2: ds_read all kh1 frags                       | barrier | 16 MFMA (kk0)
//   P3: stage KH1(s+1) 8 loads; s_waitcnt vmcnt(8)  | barrier | 16 MFMA (kk1)
// Raw s_barrier (no vmcnt(0) drains). Hazard derivation:
//  - RAW: KH0(s) reads (P0 top) guarded by vmcnt(8)@P3(s-1)+barrier (drains
//    the 8 KH0(s) loads, leaves KH1(s)'s 8 in flight). KH1(s) reads (P2 top)
//    guarded by vmcnt(8)@P1(s)+barrier. Never a full drain in the loop.
//  - WAR: all reads of a half-slot are issued before the barrier preceding
//    its re-stage issue; loads land >= barrier + MFMA + mem-latency later.
// Last step re-stages itself (identical bytes) to keep vmcnt accounting flat.
// ---------------------------------------------------------------------------
__global__ __launch_bounds__(256, 2) void tern_conv_kernel(
        const ushort_t* __restrict__ xt,    // [(NPIX+1)][256]
        const ushort_t* __restrict__ wt2,   // [256 o][9][256 c]
        const float* __restrict__ alpha,
        const float* __restrict__ bias,
        float* __restrict__ out) {
    __shared__ __align__(16) ushort_t As[2][BM * 64];   // 2 x 16 KB
    __shared__ __align__(16) ushort_t Xs[2][BN * 64];   // 2 x 16 KB

    const int tid = threadIdx.x;
    const int wv = tid >> 6;
    const int l = tid & 63;
    const int bid = blockIdx.x;
    const int o0 = (bid & 1) * BM;
    const int p0 = (bid >> 1) * BN;

    const int rthr = tid >> 3;                 // 0..31: staging row within a round
    const int g = (l & 7) ^ ((l >> 3) & 7);    // swizzled source 8-ch segment

    // per-thread staging sources: 4 row-slots, stride 32
    const ushort_t* abase[4];
    int ximg[4], xh[4], xw[4];
#pragma unroll
    for (int i = 0; i < 4; ++i) {
        abase[i] = wt2 + (size_t)(o0 + i * 32 + rthr) * K_TOT + g * 8;
        int p = p0 + i * 32 + rthr;
        int n_img = p / IMG;
        int hw_ = p - n_img * IMG;
        xh[i] = hw_ / HWDIM;
        xw[i] = hw_ - xh[i] * HWDIM;
        ximg[i] = n_img * IMG;
    }

    // wave-uniform LDS staging destinations (short offsets)
    int doff[4];
#pragma unroll
    for (int i = 0; i < 4; ++i) doff[i] = (i * 32 + (wv << 3)) << 6;

    // fragment-read geometry (identical layout/swizzle math to prior kernel)
    const int qd = l >> 4, ln = l & 15;
    const int wm = (wv >> 1) * 64, wn = (wv & 1) * 64;
    const int so0 = (qd ^ (ln & 7)) * 8;       // kk=1 chunk is so0 ^ 32
    int arow[4], xrow[4];
#pragma unroll
    for (int i = 0; i < 4; ++i) {
        arow[i] = (wm + i * 16 + ln) * 64;
        xrow[i] = (wn + i * 16 + ln) * 64;
    }

    f32x4 acc[4][4];
#pragma unroll
    for (int i = 0; i < 4; ++i)
#pragma unroll
        for (int j = 0; j < 4; ++j)
            acc[i][j] = (f32x4){0.f, 0.f, 0.f, 0.f};

    // ---- prologue: stage step 0 (c0=0, kpos=0 -> dh=dw=-1), kh0 then kh1
    {
        const ushort_t* xsrc[4];
#pragma unroll
        for (int i = 0; i < 4; ++i) {
            int h2 = xh[i] - 1, w2 = xw[i] - 1;
            int row = ((unsigned)h2 < (unsigned)HWDIM && (unsigned)w2 < (unsigned)HWDIM)
                          ? (ximg[i] + h2 * HWDIM + w2) : NPIX;
            xsrc[i] = xt + (size_t)row * CIN + g * 8;
        }
#pragma unroll
        for (int kh = 0; kh < 2; ++kh) {
#pragma unroll
            for (int i = 0; i < 4; ++i)
                __builtin_amdgcn_global_load_lds(AS1CAST(abase[i] + kh * 64),
                                                 AS3CAST(&As[kh][doff[i]]), 16, 0, 0);
#pragma unroll
            for (int i = 0; i < 4; ++i)
                __builtin_amdgcn_global_load_lds(AS1CAST(xsrc[i] + kh * 64),
                                                 AS3CAST(&Xs[kh][doff[i]]), 16, 0, 0);
        }
    }
    asm volatile("s_waitcnt vmcnt(8)" ::: "memory");   // kh0 landed, kh1 in flight
    __builtin_amdgcn_s_barrier();
    asm volatile("" ::: "memory");

#pragma unroll 1
    for (int s = 0; s < NSTEP; ++s) {
        // next-step staging parameters (clamped: last step restages itself)
        const int sn = (s + 1 < NSTEP) ? s + 1 : NSTEP - 1;
        const int c0n = (sn >= 9) ? 128 : 0;
        const int kposn = sn - ((sn >= 9) ? 9 : 0);
        const int dh = kposn / 3 - 1;
        const int dw = kposn - (dh + 1) * 3 - 1;
        const int koffn = kposn * 256 + c0n;
        const ushort_t* xsrc[4];
#pragma unroll
        for (int i = 0; i < 4; ++i) {
            int h2 = xh[i] + dh, w2 = xw[i] + dw;
            int row = ((unsigned)h2 < (unsigned)HWDIM && (unsigned)w2 < (unsigned)HWDIM)
                          ? (ximg[i] + h2 * HWDIM + w2) : NPIX;
            xsrc[i] = xt + (size_t)row * CIN + c0n + g * 8;
        }

#pragma unroll
        for (int hs = 0; hs < 2; ++hs) {
            // ---- read phase: both 32-ch chunks of half-slot hs
            bf16x8 a0[4], a1[4], x0[4], x1[4];
#pragma unroll
            for (int m = 0; m < 4; ++m) {
                a0[m] = *(const bf16x8*)&As[hs][arow[m] + so0];
                a1[m] = *(const bf16x8*)&As[hs][arow[m] + (so0 ^ 32)];
            }
#pragma unroll
            for (int n = 0; n < 4; ++n) {
                x0[n] = *(const bf16x8*)&Xs[hs][xrow[n] + so0];
                x1[n] = *(const bf16x8*)&Xs[hs][xrow[n] + (so0 ^ 32)];
            }
            asm volatile("" ::: "memory");
            __builtin_amdgcn_s_barrier();
            asm volatile("" ::: "memory");
            __builtin_amdgcn_s_setprio(1);
#pragma unroll
            for (int m = 0; m < 4; ++m)
#pragma unroll
                for (int n = 0; n < 4; ++n)
                    acc[m][n] = __builtin_amdgcn_mfma_f32_16x16x32_bf16(
                        a0[m], x0[n], acc[m][n], 0, 0, 0);
            __builtin_amdgcn_s_setprio(0);

            // ---- stage phase: prefetch half-slot hs of next step
#pragma unroll
            for (int i = 0; i < 4; ++i)
                __builtin_amdgcn_global_load_lds(AS1CAST(abase[i] + koffn + hs * 64),
                                                 AS3CAST(&As[hs][doff[i]]), 16, 0, 0);
#pragma unroll
            for (int i = 0; i < 4; ++i)
                __builtin_amdgcn_global_load_lds(AS1CAST(xsrc[i] + hs * 64),
                                                 AS3CAST(&Xs[hs][doff[i]]), 16, 0, 0);
            asm volatile("s_waitcnt vmcnt(8)" ::: "memory");  // drain prev batch only
            asm volatile("" ::: "memory");
            __builtin_amdgcn_s_barrier();
            asm volatile("" ::: "memory");
            __builtin_amdgcn_s_setprio(1);
#pragma unroll
            for (int m = 0; m < 4; ++m)
#pragma unroll
                for (int n = 0; n < 4; ++n)
                    acc[m][n] = __builtin_amdgcn_mfma_f32_16x16x32_bf16(
                        a1[m], x1[n], acc[m][n], 0, 0, 0);
            __builtin_amdgcn_s_setprio(0);
        }
    }

    // epilogue: out[n][o][h][w] = alpha[o]*acc + bias[o]
#pragma unroll
    for (int im = 0; im < 4; ++im) {
        const int orow = o0 + wm + im * 16 + qd * 4;
        const f32x4 al = *(const f32x4*)&alpha[orow];
        const f32x4 bi = *(const f32x4*)&bias[orow];
#pragma unroll
        for (int in2 = 0; in2 < 4; ++in2) {
            const int pc = p0 + wn + in2 * 16 + ln;
            const int ni = pc / IMG;
            const int hwc = pc - ni * IMG;
            const size_t obase = (size_t)ni * COUT * IMG + hwc;
#pragma unroll
            for (int rr = 0; rr < 4; ++rr)
                out[obase + (size_t)(orow + rr) * IMG] = al[rr] * acc[im][in2][rr] + bi[rr];
        }
    }
}

extern "C" void kernel_launch(void* const* d_in, const int* in_sizes, int n_in,
                              void* d_out, int out_size, void* d_ws, size_t ws_size,
                              hipStream_t stream) {
    const float* x      = (const float*)d_in[0];
    const float* weight = (const float*)d_in[1];
    const float* bias   = (const float*)d_in[2];
    float* out = (float*)d_out;

    // workspace: xt (NPIX+1)*256 bf16 (last row = zero halo), wt2, alpha
    ushort_t* xt     = (ushort_t*)d_ws;
    ushort_t* wt2    = (ushort_t*)((char*)d_ws + (size_t)(NPIX + 1) * CIN * sizeof(ushort_t));
    float*    alphav = (float*)((char*)wt2 + (size_t)COUT * K_TOT * sizeof(ushort_t));

    ternarize_kernel<<<COUT, 256, 0, stream>>>(weight, wt2, alphav,
                                               xt + (size_t)NPIX * CIN);

    dim3 tg(IMG / 32, CIN / 128, NIMG);  // 98 x 2 x 32
    transpose_kernel<<<tg, 256, 0, stream>>>(x, xt);

    const int n_blocks = (COUT / BM) * (NPIX / BN);  // 1568
    tern_conv_kernel<<<n_blocks, 256, 0, stream>>>(xt, wt2, alphav, bias, out);
}